// Round 8
// baseline (791.057 us; speedup 1.0000x reference)
//
#include <hip/hip_runtime.h>
#include <stdint.h>

// Net_18021682774696 — MTGNN-ish: 3x { TCN(2 gated units) ; skip ; 3x mixprop ; LN+ReLU } + end convs.
// Round 13: co-scheduled layer chains. kfront = prop-hop1 (z<3) + fused TCN2 (z==3);
// kback = prop-hop2 (z<3) + skip-GEMM (z==3). The TCN/skip chains are data-independent
// of the prop chain within a layer (R6=R7 proved tcn2 fusion time-neutral); embedding
// them as extra blocks in the prop launches removes ~35-45us/layer of serialized
// low-occupancy dispatches. Per-layer: 5 dispatches -> 2 (+combine+apply).

typedef uint16_t u16;
typedef uint32_t u32;
typedef __attribute__((ext_vector_type(8))) short s8v;
typedef __attribute__((ext_vector_type(4))) float f4v;

#define MFMA16(a,b,c) __builtin_amdgcn_mfma_f32_16x16x32_bf16(a,b,c,0,0,0)

__device__ __forceinline__ float b2f(u16 u){ union{u32 i; float f;} x; x.i=(u32)u<<16; return x.f; }
__device__ __forceinline__ u16 f2b(float f){
  u32 u = __builtin_bit_cast(u32, f);
  u32 r = (u + 0x7fffu + ((u >> 16) & 1u)) >> 16;   // RNE
  return (u16)r;
}

// async global->LDS, 16B per lane; LDS dest is wave-uniform base + lane*16.
__device__ __forceinline__ void gld16(const void* g, void* l) {
  __builtin_amdgcn_global_load_lds(
      (const __attribute__((address_space(1))) void*)g,
      (__attribute__((address_space(3))) void*)l, 16, 0, 0);
}

// ---------------------------------------------------------------------------
// kdetect: fp32 (flag=1) vs bf16 (flag=0). 32 blocks scan 128 KB; atomicOr.
// ---------------------------------------------------------------------------
__global__ __launch_bounds__(256) void kdetect(const u16* __restrict__ x, int* __restrict__ flag)
{
  const int i = blockIdx.x*256 + threadIdx.x;
  const uint4 v = ((const uint4*)x)[i];
  const u32 w[4] = {v.x, v.y, v.z, v.w};
  int cnt = 0;
  #pragma unroll
  for (int e = 0; e < 4; e++) {
    if ((w[e] & 0x7F80u) == 0x7F80u) cnt++;
    if (((w[e] >> 16) & 0x7F80u) == 0x7F80u) cnt++;
  }
  const unsigned long long m = __ballot(cnt != 0);
  if (m && (threadIdx.x & 63) == 0) atomicOr(flag, 1);
}

// kcvt4: canonicalize one array into bf16 (4 elements/thread). fp32 path only.
__global__ __launch_bounds__(256) void kcvt4(const void* __restrict__ src, u16* __restrict__ dst,
                                             int n4, const int* __restrict__ flag)
{
  if (!*flag) return;
  const int i = blockIdx.x*256 + threadIdx.x;
  if (i >= n4) return;
  const float4 v = ((const float4*)src)[i];
  u16 o[4]; o[0]=f2b(v.x); o[1]=f2b(v.y); o[2]=f2b(v.z); o[3]=f2b(v.w);
  *(uint2*)(dst + (long)i*4) = *(uint2*)o;
}

// kcvt_small: 18 small weight inputs in one launch.
struct CvtTab { const void* s[18]; u16* d[18]; int n4[18]; };
__global__ __launch_bounds__(256) void kcvt_small(CvtTab tb, const int* __restrict__ flag)
{
  const int e = blockIdx.y;
  const int i = blockIdx.x*256 + threadIdx.x;
  if (i >= tb.n4[e]) return;
  if (*flag) {
    const float4 v = ((const float4*)tb.s[e])[i];
    u16 o[4]; o[0]=f2b(v.x); o[1]=f2b(v.y); o[2]=f2b(v.z); o[3]=f2b(v.w);
    *(uint2*)(tb.d[e] + (long)i*4) = *(uint2*)o;
  } else {
    *(uint2*)(tb.d[e] + (long)i*4) = ((const uint2*)tb.s[e])[i];
  }
}

// ---------------------------------------------------------------------------
// kcvtT: dy -> dyb (fp32 path) + dytb (transposed) + row/col sums.
//   64x128 tile per block, grid (16,32,8). (R7 version)
// ---------------------------------------------------------------------------
__global__ __launch_bounds__(256) void kcvtT(
    const void* __restrict__ src, u16* __restrict__ dyb, u16* __restrict__ dytb,
    float* __restrict__ rsum, float* __restrict__ csum, const int* __restrict__ flag)
{
  __shared__ alignas(16) u32 tt[2][64][32];
  const int tid = threadIdx.x;
  const int b = blockIdx.z;
  const long r0 = (long)blockIdx.y*64;
  const long c0 = (long)blockIdx.x*128;
  const int rp = tid>>3, cg8 = (tid&7)*8;   // row-pair 0..31, col-group
  const long base = (long)b*4194304;
  const int fl = *flag;

  float rsl = 0.f, rsh = 0.f;
  #pragma unroll
  for (int h = 0; h < 2; h++) {
    u16 lo[8], hi[8];
    const long gl = base + (r0 + 2*rp)*2048 + c0 + h*64 + cg8;
    const long gh = gl + 2048;
    if (fl) {
      const float* sl = (const float*)src + gl;
      const float* sh = (const float*)src + gh;
      const float4 a0 = ((const float4*)sl)[0], a1 = ((const float4*)sl)[1];
      const float4 b0 = ((const float4*)sh)[0], b1 = ((const float4*)sh)[1];
      lo[0]=f2b(a0.x); lo[1]=f2b(a0.y); lo[2]=f2b(a0.z); lo[3]=f2b(a0.w);
      lo[4]=f2b(a1.x); lo[5]=f2b(a1.y); lo[6]=f2b(a1.z); lo[7]=f2b(a1.w);
      hi[0]=f2b(b0.x); hi[1]=f2b(b0.y); hi[2]=f2b(b0.z); hi[3]=f2b(b0.w);
      hi[4]=f2b(b1.x); hi[5]=f2b(b1.y); hi[6]=f2b(b1.z); hi[7]=f2b(b1.w);
      *(uint4*)(dyb + gl) = *(uint4*)lo;   // bf16 copy needed only when converting
      *(uint4*)(dyb + gh) = *(uint4*)hi;
    } else {
      *(uint4*)lo = *((const uint4*)((const u16*)src + gl));
      *(uint4*)hi = *((const uint4*)((const u16*)src + gh));
    }
    #pragma unroll
    for (int e = 0; e < 8; e++) {
      rsl += b2f(lo[e]); rsh += b2f(hi[e]);
      const int c = cg8 + e;
      tt[h][c][rp ^ ((c & 0x38) >> 1)] = (u32)lo[e] | ((u32)hi[e] << 16);
    }
  }
  rsl += __shfl_down(rsl, 4, 8); rsl += __shfl_down(rsl, 2, 8); rsl += __shfl_down(rsl, 1, 8);
  rsh += __shfl_down(rsh, 4, 8); rsh += __shfl_down(rsh, 2, 8); rsh += __shfl_down(rsh, 1, 8);
  if ((tid & 7) == 0) {
    atomicAdd(rsum + b*2048 + r0 + 2*rp,     rsl);
    atomicAdd(rsum + b*2048 + r0 + 2*rp + 1, rsh);
  }
  __syncthreads();

  // phase 2 (per 64-col half): thread -> output row c, 16 input rows from 2*j4.
  #pragma unroll
  for (int h = 0; h < 2; h++) {
    const int c = tid>>2, j4 = (tid&3)*8;
    const int sw = (c & 0x38) >> 1;
    u32 q[8];
    *(uint4*)&q[0] = *(const uint4*)&tt[h][c][j4 ^ sw];
    *(uint4*)&q[4] = *(const uint4*)&tt[h][c][(j4 + 4) ^ sw];
    float cs = 0.f;
    #pragma unroll
    for (int e = 0; e < 8; e++) { cs += b2f((u16)q[e]); cs += b2f((u16)(q[e] >> 16)); }
    cs += __shfl_down(cs, 2, 4); cs += __shfl_down(cs, 1, 4);
    u16* dp = dytb + base + (c0 + h*64 + c)*2048 + r0 + 2*j4;
    *(uint4*)(dp)     = *(uint4*)&q[0];
    *(uint4*)(dp + 8) = *(uint4*)&q[4];
    if ((tid & 3) == 0) atomicAdd(csum + b*2048 + c0 + h*64 + c, cs);
  }
}

__global__ void kfin(float* __restrict__ v){   // v = 1/(1+v)
  const int i = blockIdx.x*256 + threadIdx.x;
  v[i] = 1.f/(1.f + v[i]);
}

// ---------------------------------------------------------------------------
// prop_body: 3-graph propagation hop (R4-proven), as a device function so it
// can be embedded in the co-scheduled launches. blockIdx.z = graph (0..2).
// ---------------------------------------------------------------------------
struct PG {
  const u16* Ac0; const u16* Ac1; const u16* Ac2;   // converted bf16
  const u16* Ar0; const u16* Ar1;                   // raw inputs (bf16 fast path)
  const int* flag;
  long ab0, ab1, ab2;
  const u16* X0; const u16* X1; const u16* X2;
  const float* R0; const float* R1; const float* R2;
  long rb0, rb1, rb2;
  u16* O0; u16* O1; u16* O2;
};

__device__ __forceinline__ void prop_body(
    const PG& p, long x_bs, long o_bs,
    u16 (&Al)[4][64][64], u16 (&Xl)[4][32][64])
{
  const int tid = threadIdx.x, wave = tid>>6, lane = tid&63;
  const int lw = lane&15, quad = lane>>4;
  const int wr = wave>>1, wc = wave&1;
  const int v0 = blockIdx.x*64;
  const int b = blockIdx.y, g = blockIdx.z;
  const int fl = *p.flag;
  const u16* Ag; long ab; const u16* Xg; const float* Rg; long rb; u16* Og;
  if (g == 0)      { Ag = fl ? p.Ac0 : p.Ar0; ab = p.ab0; Xg = p.X0; Rg = p.R0; rb = p.rb0; Og = p.O0; }
  else if (g == 1) { Ag = fl ? p.Ac1 : p.Ar1; ab = p.ab1; Xg = p.X1; Rg = p.R1; rb = p.rb1; Og = p.O1; }
  else             { Ag = p.Ac2;              ab = p.ab2; Xg = p.X2; Rg = p.R2; rb = p.rb2; Og = p.O2; }
  const u16* Ab = Ag + (long)b*ab;
  const u16* Xb = Xg + (long)b*x_bs;

  // staging decode: wave-uniform LDS base + lane*16; source col pre-swizzled.
  const int srow = wave*8 + (lane>>3);          // 0..31 within a 32-row group
  const int skc  = lane&7;
  const long soff = (long)((skc ^ (srow&7))*8); // swizzled 8-elem column
  const u16* srcA0 = Ab + (long)(v0 + srow)*2048 + soff;        // rows  0..31
  const u16* srcA1 = Ab + (long)(v0 + 32 + srow)*2048 + soff;   // rows 32..63
  const u16* srcX  = Xb + (long)srow*2048 + soff;               // c rows 0..31

#define STAGE(tt) do { const int bb_=(tt)&3; const long k0_=(long)(tt)*64;          \
    gld16(srcA0 + k0_, (void*)((char*)&Al[bb_][0][0]  + wave*1024));                \
    gld16(srcA1 + k0_, (void*)((char*)&Al[bb_][32][0] + wave*1024));                \
    gld16(srcX  + k0_, (void*)((char*)&Xl[bb_][0][0]  + wave*1024)); } while(0)

  f4v acc0 = {0.f,0.f,0.f,0.f}, acc1 = {0.f,0.f,0.f,0.f};
  const int arow0 = wr*32 + lw;
  const int arow1 = wr*32 + 16 + lw;
  const int xrow  = wc*16 + lw;
  const int sw    = lw & 7;              // arow0&7 == arow1&7 == xrow&7 == lw&7
  const int q0    = (quad ^ sw)*8;       // k32=0 slot (elems)
  const int q1    = ((quad ^ sw) ^ 4)*8; // k32=1 slot

  STAGE(0); STAGE(1); STAGE(2);          // 9 loads in flight per wave

  #pragma unroll 1
  for (int t = 0; t < 32; t++) {
    if (t < 30)       asm volatile("s_waitcnt vmcnt(6)" ::: "memory");
    else if (t == 30) asm volatile("s_waitcnt vmcnt(3)" ::: "memory");
    else              asm volatile("s_waitcnt vmcnt(0)" ::: "memory");
    __builtin_amdgcn_s_barrier();
    __builtin_amdgcn_sched_barrier(0);
    const int bb = t&3;
    s8v x0  = *(const s8v*)&Xl[bb][xrow][q0];
    s8v a00 = *(const s8v*)&Al[bb][arow0][q0];
    s8v a10 = *(const s8v*)&Al[bb][arow1][q0];
    s8v x1  = *(const s8v*)&Xl[bb][xrow][q1];
    s8v a01 = *(const s8v*)&Al[bb][arow0][q1];
    s8v a11 = *(const s8v*)&Al[bb][arow1][q1];
    acc0 = MFMA16(a00, x0, acc0);
    acc1 = MFMA16(a10, x0, acc1);
    acc0 = MFMA16(a01, x1, acc0);
    acc1 = MFMA16(a11, x1, acc1);
    if (t <= 28) STAGE(t+3);
  }
#undef STAGE

  // epilogue: wave owns 32v x 16c; D[row=quad*4+r, col=lw] per fragment.
  const int c = wc*16 + lw;
  const float* rp = Rg + (long)b*rb;
  u16* ob = Og + (long)b*o_bs;
  #pragma unroll
  for (int f = 0; f < 2; f++) {
    const f4v s = f ? acc1 : acc0;
    const int vb = v0 + wr*32 + f*16 + quad*4;
    const u16* dp = Xb + (long)c*2048 + vb;
    u16 pk[4];
    #pragma unroll
    for (int r = 0; r < 4; r++) pk[r] = f2b((s[r] + b2f(dp[r])) * rp[vb + r]);
    *(uint2*)(ob + (long)c*2048 + vb) = *(uint2*)pk;
  }
}

// ---------------------------------------------------------------------------
// kfront: z<3 -> prop hop1; z==3 -> fused 2-unit gated TCN (hid -> hb2).
// ---------------------------------------------------------------------------
struct FR {
  PG p;
  const u16 *H, *Wf1, *bf1, *Wg1, *bg1, *Wf2, *bf2, *Wg2, *bg2;
  u16* out;
};

__global__ __launch_bounds__(256) void kfront(FR f, long x_bs, long o_bs)
{
  __shared__ alignas(16) u16 Al[4][64][64];
  __shared__ alignas(16) u16 Xl[4][32][64];
  if (blockIdx.z < 3) { prop_body(f.p, x_bs, o_bs, Al, Xl); return; }

  // --- TCN2 branch (256 blocks: bid = y*32 + x) ---
  u16 (*h1)[16][136] = reinterpret_cast<u16 (*)[16][136]>(&Al[0][0][0]);
  const int tid = threadIdx.x, wave = tid>>6, lane = tid&63, lw = lane&15, quad = lane>>4;
  const int bid = blockIdx.y*32 + blockIdx.x;
  const long j0 = (long)bid*64 + wave*16;
  const f4v zero = {0.f,0.f,0.f,0.f};
  f4v accf[8], accg[8];
  #pragma unroll
  for (int nt=0; nt<8; nt++){ accf[nt] = zero; accg[nt] = zero; }
  const u16* Arow = f.H + (j0 + lw)*128 + quad*8;
  #pragma unroll
  for (int k0 = 0; k0 < 128; k0 += 32) {
    s8v a = *(const s8v*)(Arow + k0);
    #pragma unroll
    for (int nt = 0; nt < 8; nt++) {
      const int o = nt*16 + lw;
      s8v bf_ = *(const s8v*)(f.Wf1 + o*128 + k0 + quad*8);
      s8v bg_ = *(const s8v*)(f.Wg1 + o*128 + k0 + quad*8);
      accf[nt] = MFMA16(a, bf_, accf[nt]);
      accg[nt] = MFMA16(a, bg_, accg[nt]);
    }
  }
  #pragma unroll
  for (int nt = 0; nt < 8; nt++) {
    const int o = nt*16 + lw;
    const float fb = b2f(f.bf1[o]), gb = b2f(f.bg1[o]);
    #pragma unroll
    for (int rr = 0; rr < 4; rr++) {
      const float ff = accf[nt][rr] + fb, gg = accg[nt][rr] + gb;
      const float e2 = __expf(2.f*ff);
      const float th = 1.f - 2.f/(e2 + 1.f);
      const float sg = 1.f/(1.f + __expf(-gg));
      h1[wave][quad*4 + rr][o] = f2b(th*sg);
    }
  }
  __syncthreads();
  #pragma unroll
  for (int nt=0; nt<8; nt++){ accf[nt] = zero; accg[nt] = zero; }
  #pragma unroll
  for (int k0 = 0; k0 < 128; k0 += 32) {
    s8v a = *(const s8v*)&h1[wave][lw][k0 + quad*8];
    #pragma unroll
    for (int nt = 0; nt < 8; nt++) {
      const int o = nt*16 + lw;
      s8v bf_ = *(const s8v*)(f.Wf2 + o*128 + k0 + quad*8);
      s8v bg_ = *(const s8v*)(f.Wg2 + o*128 + k0 + quad*8);
      accf[nt] = MFMA16(a, bf_, accf[nt]);
      accg[nt] = MFMA16(a, bg_, accg[nt]);
    }
  }
  #pragma unroll
  for (int nt = 0; nt < 8; nt++) {
    const int o = nt*16 + lw;
    const float fb = b2f(f.bf2[o]), gb = b2f(f.bg2[o]);
    #pragma unroll
    for (int rr = 0; rr < 4; rr++) {
      const long j = j0 + quad*4 + rr;
      const float ff = accf[nt][rr] + fb, gg = accg[nt][rr] + gb;
      const float e2 = __expf(2.f*ff);
      const float th = 1.f - 2.f/(e2 + 1.f);
      const float sg = 1.f/(1.f + __expf(-gg));
      f.out[j*128 + o] = f2b(th*sg);
    }
  }
}

// ---------------------------------------------------------------------------
// kback: z<3 -> prop hop2; z==3 -> skip-GEMM (hb2 @ skW^T + skb [+ prev skip]).
// ---------------------------------------------------------------------------
struct BK {
  PG p;
  const u16* A; const u16* W; const u16* bias;
  float* skipbuf; int addprev;
};

__global__ __launch_bounds__(256) void kback(BK k, long x_bs, long o_bs)
{
  __shared__ alignas(16) u16 Al[4][64][64];
  __shared__ alignas(16) u16 Xl[4][32][64];
  if (blockIdx.z < 3) { prop_body(k.p, x_bs, o_bs, Al, Xl); return; }

  // --- skip branch (256 blocks) ---
  const int tid = threadIdx.x, wave = tid>>6, lane = tid&63, lw = lane&15, quad = lane>>4;
  const int bid = blockIdx.y*32 + blockIdx.x;
  const long j0 = (long)bid*64 + wave*16;
  const f4v zero = {0.f,0.f,0.f,0.f};
  f4v acc[16];
  #pragma unroll
  for (int nt=0; nt<16; nt++) acc[nt] = zero;
  const u16* Arow = k.A + (j0 + lw)*128 + quad*8;
  #pragma unroll
  for (int k0 = 0; k0 < 128; k0 += 32) {
    s8v a = *(const s8v*)(Arow + k0);
    #pragma unroll
    for (int nt = 0; nt < 16; nt++) {
      const int o = nt*16 + lw;
      s8v b = *(const s8v*)(k.W + (long)o*128 + k0 + quad*8);
      acc[nt] = MFMA16(a, b, acc[nt]);
    }
  }
  #pragma unroll
  for (int nt = 0; nt < 16; nt++) {
    const int o = nt*16 + lw;
    const float bv = b2f(k.bias[o]);
    #pragma unroll
    for (int rr = 0; rr < 4; rr++) {
      const long j = j0 + quad*4 + rr;
      float v = acc[nt][rr] + bv;
      if (k.addprev) v += k.skipbuf[j*256 + o];
      k.skipbuf[j*256 + o] = v;
    }
  }
}

// ---------------------------------------------------------------------------
// kprop (LDS-staged, TRANSA=1 combine pass), MODE 1:
//   out1[c][v] = acc + bias[c] + D[c,v] -> f32; block (sum,sumsq) fused into
//   epilogue (atomicAdd to stats[ball*2..+1]).
// ---------------------------------------------------------------------------
template<int TRANSA, int MODE>
__global__ __launch_bounds__(256) void kprop(
    const u16* __restrict__ A, long a_bs, int lda, int K,
    const u16* __restrict__ X, long x_bs, int ldx,
    const u16* __restrict__ D, long d_bs,
    const float* __restrict__ rinv, long r_bs,
    const float* __restrict__ bias,
    u16* __restrict__ out0, float* __restrict__ out1, long o_bs,
    float* __restrict__ stats)
{
  __shared__ u16 As[4][2][16][40];
  __shared__ f4v red[4][2][64];
  const int tid = threadIdx.x;
  const int wave = tid >> 6, lane = tid & 63;
  const int lw = lane & 15, quad = lane >> 4;
  const int v0 = blockIdx.x * 16;
  const int ball = blockIdx.z + blockIdx.y;
  const u16* Ab = A + (long)ball * a_bs;
  const u16* Xb = X + (long)ball * x_bs;
  const int KC = K >> 5;

  f4v acc0 = {0.f,0.f,0.f,0.f}, acc1 = {0.f,0.f,0.f,0.f};

  int r0, c0_;
  if (TRANSA == 0) { r0 = lane >> 2; c0_ = (lane & 3) * 8; }
  else             { r0 = lane >> 1; c0_ = (lane & 1) * 8; }

  int ci = wave;
  bool has = ci < KC;
  uint4 d = make_uint4(0,0,0,0);
  if (has) {
    d = (TRANSA == 0)
      ? *(const uint4*)(Ab + (long)(v0 + r0) * lda + ci * 32 + c0_)
      : *(const uint4*)(Ab + (long)(ci * 32 + r0) * lda + v0 + c0_);
  }
  int buf = 0;
  while (has) {
    if (TRANSA == 0) {
      *(uint4*)&As[wave][buf][r0][c0_] = d;
    } else {
      u16 tmp[8]; *(uint4*)tmp = d;
      #pragma unroll
      for (int e = 0; e < 8; e++) As[wave][buf][c0_ + e][r0] = tmp[e];
    }
    const int cn = ci + 4;
    const bool hn = cn < KC;
    if (hn) {
      d = (TRANSA == 0)
        ? *(const uint4*)(Ab + (long)(v0 + r0) * lda + cn * 32 + c0_)
        : *(const uint4*)(Ab + (long)(cn * 32 + r0) * lda + v0 + c0_);
    }
    s8v af = *(const s8v*)&As[wave][buf][lw][quad * 8];
    const u16* xk = Xb + ci * 32 + quad * 8;
    s8v b0 = *(const s8v*)(xk + (long)lw * ldx);
    s8v b1 = *(const s8v*)(xk + (long)(16 + lw) * ldx);
    acc0 = MFMA16(af, b0, acc0);
    acc1 = MFMA16(af, b1, acc1);
    ci = cn; has = hn; buf ^= 1;
  }
  red[wave][0][lane] = acc0;
  red[wave][1][lane] = acc1;
  __syncthreads();
  if (wave == 0) {
    const int vb = v0 + quad * 4;
    float ssum = 0.f, sq = 0.f;
    #pragma unroll
    for (int nt = 0; nt < 2; nt++) {
      f4v a = red[0][nt][lane] + red[1][nt][lane] + red[2][nt][lane] + red[3][nt][lane];
      const int c = nt * 16 + lw;
      const u16* dp = D + (long)ball * d_bs + (long)c * 2048 + vb;
      if (MODE == 0) {
        const float* rp = rinv + (long)ball * r_bs + vb;
        u16 pk[4];
        #pragma unroll
        for (int r = 0; r < 4; r++) pk[r] = f2b((a[r] + b2f(dp[r])) * rp[r]);
        *(uint2*)(out0 + (long)ball * o_bs + (long)c * 2048 + vb) = *(uint2*)pk;
      } else {
        const float bs = bias[c];
        float4 st;
        st.x = a[0] + bs + b2f(dp[0]);
        st.y = a[1] + bs + b2f(dp[1]);
        st.z = a[2] + bs + b2f(dp[2]);
        st.w = a[3] + bs + b2f(dp[3]);
        *(float4*)(out1 + (long)ball * o_bs + (long)c * 2048 + vb) = st;
        ssum += st.x + st.y + st.z + st.w;
        sq   += st.x*st.x + st.y*st.y + st.z*st.z + st.w*st.w;
      }
    }
    if (MODE == 1) {
      #pragma unroll
      for (int off = 32; off; off >>= 1) {
        ssum += __shfl_down(ssum, off, 64);
        sq   += __shfl_down(sq,   off, 64);
      }
      if (lane == 0) {
        atomicAdd(stats + ball*2,     ssum);
        atomicAdd(stats + ball*2 + 1, sq);
      }
    }
  }
}

// ---------------------------------------------------------------------------
// kskip (LDS-free, standalone; used for the final skipE pass, mode 1).
// ---------------------------------------------------------------------------
__global__ __launch_bounds__(256) void kskip(
    const u16* __restrict__ A, int lda, int K,
    const u16* __restrict__ W, int ldb,
    const u16* __restrict__ bias,
    float* __restrict__ skipbuf, int addprev, int mode, u16* __restrict__ outb)
{
  const int tid = threadIdx.x, wave = tid>>6, lane = tid&63, lw = lane&15, quad = lane>>4;
  const long j0 = (long)blockIdx.x*64 + wave*16;
  const f4v zero = {0.f,0.f,0.f,0.f};
  f4v acc[16];
  #pragma unroll
  for (int nt=0; nt<16; nt++) acc[nt] = zero;
  const u16* Arow = A + (j0 + lw)*(long)lda + quad*8;
  for (int k0 = 0; k0 < K; k0 += 32) {
    s8v a = *(const s8v*)(Arow + k0);
    #pragma unroll
    for (int nt = 0; nt < 16; nt++) {
      const int o = nt*16 + lw;
      s8v b = *(const s8v*)(W + (long)o*ldb + k0 + quad*8);
      acc[nt] = MFMA16(a, b, acc[nt]);
    }
  }
  #pragma unroll
  for (int nt = 0; nt < 16; nt++) {
    const int o = nt*16 + lw;
    const float bv = b2f(bias[o]);
    #pragma unroll
    for (int rr = 0; rr < 4; rr++) {
      const long j = j0 + quad*4 + rr;
      float v = acc[nt][rr] + bv;
      if (addprev) v += skipbuf[j*256 + o];
      if (mode == 0) skipbuf[j*256 + o] = v;
      else           outb[j*256 + o] = f2b(v);
    }
  }
}

// ---------------------------------------------------------------------------
// kend (LDS-free): out[b,t,n] = xs@endW^T + end_b.  N=12, K=256.
// ---------------------------------------------------------------------------
__global__ __launch_bounds__(256) void kend(
    const u16* __restrict__ A, const u16* __restrict__ W, const u16* __restrict__ bias,
    void* __restrict__ outv, const int* __restrict__ flag)
{
  const int tid = threadIdx.x, wave = tid>>6, lane = tid&63, lw = lane&15, quad = lane>>4;
  const long j0 = (long)blockIdx.x*64 + wave*16;
  f4v acc = {0.f,0.f,0.f,0.f};
  const u16* Arow = A + (j0 + lw)*256 + quad*8;
  #pragma unroll
  for (int k0 = 0; k0 < 256; k0 += 32) {
    s8v a = *(const s8v*)(Arow + k0);
    s8v b = {0,0,0,0,0,0,0,0};
    if (lw < 12) b = *(const s8v*)(W + lw*256 + k0 + quad*8);
    acc = MFMA16(a, b, acc);
  }
  if (lw < 12) {
    const float bv = b2f(bias[lw]);
    const int fl = *flag;
    #pragma unroll
    for (int rr = 0; rr < 4; rr++) {
      const long j = j0 + quad*4 + rr;
      const long oi = (j >> 11)*24576 + lw*2048 + (j & 2047);
      const float val = acc[rr] + bv;
      if (fl) ((float*)outv)[oi] = val;
      else    ((u16*)outv)[oi]   = f2b(val);
    }
  }
}

// ---------------------------------------------------------------------------
// khid0: fused convert+transpose of {x, spat, tde, twe} -> hid (channel-last)
//        and x -> pbuf slot0 (channel-first bf16).
// ---------------------------------------------------------------------------
__global__ __launch_bounds__(256) void khid0(
    const void* __restrict__ x, const void* __restrict__ spat,
    const void* __restrict__ tde, const void* __restrict__ twe,
    u16* __restrict__ hid, u16* __restrict__ slot0, const int* __restrict__ flag)
{
  __shared__ u16 t[32][72];
  const int tid = threadIdx.x, b = blockIdx.y, v0 = blockIdx.x*64;
  const int fl = *flag;
  const void* srcs[4] = {x, spat, tde, twe};
  #pragma unroll
  for (int e = 0; e < 4; e++) {
    const int c = tid>>3, v8 = (tid&7)*8;
    const long boff = (long)c*2048 + v0 + v8;
    u16 o8[8];
    if (fl) {
      const float* sp = (const float*)srcs[e] + (long)b*65536 + boff;
      const float4 a = ((const float4*)sp)[0], bb = ((const float4*)sp)[1];
      o8[0]=f2b(a.x); o8[1]=f2b(a.y); o8[2]=f2b(a.z); o8[3]=f2b(a.w);
      o8[4]=f2b(bb.x); o8[5]=f2b(bb.y); o8[6]=f2b(bb.z); o8[7]=f2b(bb.w);
    } else {
      *(uint4*)o8 = *(const uint4*)((const u16*)srcs[e] + (long)b*65536 + boff);
    }
    if (e == 0) *(uint4*)(slot0 + (long)b*458752 + boff) = *(uint4*)o8;
    *(uint4*)&t[c][v8] = *(uint4*)o8;
    __syncthreads();
    const int jl = tid>>2, c8 = (tid&3)*8;
    u16 q8[8];
    #pragma unroll
    for (int i = 0; i < 8; i++) q8[i] = t[c8 + i][jl];
    *(uint4*)(hid + ((long)b*2048 + v0 + jl)*128 + e*32 + c8) = *(uint4*)q8;
    __syncthreads();
  }
}

// krowsum: row sums of the static graph; picks converted vs raw source by flag.
__global__ __launch_bounds__(256) void krowsum(const u16* __restrict__ srcA, const u16* __restrict__ srcB,
                                               const int* __restrict__ flag,
                                               float* __restrict__ outv, int nrows)
{
  const u16* src = (*flag) ? srcA : srcB;
  const int wave = threadIdx.x>>6, lane = threadIdx.x&63;
  const int row = blockIdx.x*4 + wave;
  if (row >= nrows) return;
  const u16* p = src + (long)row*2048 + lane*8;
  float s = 0.f;
  #pragma unroll
  for (int it = 0; it < 4; it++) {
    u16 v[8]; *(uint4*)v = *(const uint4*)(p + it*512);
    #pragma unroll
    for (int e = 0; e < 8; e++) s += b2f(v[e]);
  }
  #pragma unroll
  for (int off = 32; off; off >>= 1) s += __shfl_down(s, off, 64);
  if (lane == 0) outv[row] = 1.f/(1.f + s);
}

// kweff: all 3 layers in one dispatch (blockIdx.y = layer). Prologue-only.
__global__ __launch_bounds__(256) void kweff(
    const u16* __restrict__ g0W, const u16* __restrict__ g1W, const u16* __restrict__ g2W,
    const u16* __restrict__ g0b, const u16* __restrict__ g1b, const u16* __restrict__ g2b,
    u16* __restrict__ weffA, float* __restrict__ bwA)
{
  const int L = blockIdx.y;
  const int ioff = L*3072, boff = L*32;
  u16* weff = weffA + L*7168;
  float* bw = bwA + L*32;
  const int idx = blockIdx.x*256 + threadIdx.x;
  if (idx < 32) bw[idx] = b2f(g0b[boff+idx]) + b2f(g1b[boff+idx]) + b2f(g2b[boff+idx]);
  if (idx >= 7168) return;
  const int o = idx / 224, m = idx % 224;
  const u16* Ws[3] = {g0W + ioff, g1W + ioff, g2W + ioff};
  float val;
  if (m < 32) {
    val = 0.f;
    #pragma unroll
    for (int g = 0; g < 3; g++) {
      const float w0 = b2f(Ws[g][o*96 + m]);
      const float w1 = b2f(Ws[g][o*96 + 32 + m]);
      const float w2 = b2f(Ws[g][o*96 + 64 + m]);
      val += w0 + 0.05f*(w1 + w2);
    }
  } else {
    const int f = (m - 32) >> 5, cc = m & 31;
    const int g = f >> 1, typ = f & 1;
    const float w1 = b2f(Ws[g][o*96 + 32 + cc]);
    const float w2 = b2f(Ws[g][o*96 + 64 + cc]);
    val = (typ == 0) ? (0.95f*w1 + 0.0475f*w2) : (0.9025f*w2);
  }
  weff[o*224 + m] = f2b(val);
}

__global__ __launch_bounds__(256) void kapply(
    const float* __restrict__ xpre, const float* __restrict__ raw,
    const u16* __restrict__ nw, const u16* __restrict__ nb,
    u16* __restrict__ slot0, u16* __restrict__ hid)
{
  __shared__ u16 t[32][72];
  const int tid = threadIdx.x, b = blockIdx.y, v0 = blockIdx.x*64;
  const float mu = raw[b*2] * (1.f/65536.f);
  const float var = raw[b*2+1] * (1.f/65536.f) - mu*mu;
  const float rs = rsqrtf(var + 1e-5f);
  const int c = tid>>3, v8 = (tid&7)*8;
  const long boff = (long)c*2048 + v0 + v8;
  float4 xa = *(const float4*)(xpre + (long)b*65536 + boff);
  float4 xbv = *(const float4*)(xpre + (long)b*65536 + boff + 4);
  u16 wv[8], bv[8], o8[8];
  *(uint4*)wv = *(const uint4*)(nw + boff);
  *(uint4*)bv = *(const uint4*)(nb + boff);
  const float xs[8] = {xa.x, xa.y, xa.z, xa.w, xbv.x, xbv.y, xbv.z, xbv.w};
  #pragma unroll
  for (int e = 0; e < 8; e++) {
    float y = (xs[e] - mu) * rs * b2f(wv[e]) + b2f(bv[e]);
    y = fmaxf(y, 0.f);
    o8[e] = f2b(y);
    t[c][v8 + e] = o8[e];
  }
  *(uint4*)(slot0 + (long)b*458752 + boff) = *(uint4*)o8;
  __syncthreads();
  const int jl = tid>>2, c8 = (tid&3)*8;
  u16 q8[8];
  #pragma unroll
  for (int e = 0; e < 8; e++) q8[e] = t[c8 + e][jl];
  *(uint4*)(hid + ((long)b*2048 + v0 + jl)*128 + c8) = *(uint4*)q8;
}

// ---------------------------------------------------------------------------
extern "C" void kernel_launch(void* const* d_in, const int* in_sizes, int n_in,
                              void* d_out, int out_size, void* d_ws, size_t ws_size,
                              hipStream_t stream)
{
  (void)in_sizes; (void)n_in; (void)out_size; (void)ws_size;

  char* ws = (char*)d_ws;
  u16*   pbuf = (u16*)(ws + 0);          // [8][7][32][2048] bf16
  u16*   hid  = (u16*)(ws + 7340032);    // [16384][128] bf16
  u16*   hb2  = (u16*)(ws + 15728640);
  float* skip = (float*)(ws + 19922944); // [16384][256] f32
  u16*   xsb  = (u16*)(ws + 36700160);   // [16384][256] bf16
  float* xpre = (float*)(ws + 45088768); // [8][32][2048] f32
  float* rst  = (float*)(ws + 47203328); // [2048]
  float* rdy  = (float*)(ws + 47211520); // [8][2048]  (contiguous with cdy)
  float* cdy  = (float*)(ws + 47277056); // [8][2048]
  int*   flag = (int*)(ws + 47343616);
  float* raw  = (float*)(ws + 47343744); // [3][16] LN partials

  size_t coff = 50331648;
  auto alloc = [&](size_t elems) -> u16* {
    u16* p = (u16*)(ws + coff);
    coff += ((elems*2 + 255)/256)*256;
    return p;
  };
  u16* dyb   = alloc(33554432);
  u16* stgb  = alloc(4194304);
  u16* encWf = alloc(98304);
  u16* encbf = alloc(768);
  u16* encWg = alloc(98304);
  u16* encbg = alloc(768);
  u16* skW   = alloc(98304);
  u16* skb   = alloc(768);
  u16* nw    = alloc(196608);
  u16* nb    = alloc(196608);
  u16* g0W   = alloc(9216);
  u16* g0b   = alloc(96);
  u16* g1W   = alloc(9216);
  u16* g1b   = alloc(96);
  u16* g2W   = alloc(9216);
  u16* g2b   = alloc(96);
  u16* sEW   = alloc(8192);
  u16* sEb   = alloc(256);
  u16* eW    = alloc(3072);
  u16* eb    = alloc(12);
  u16* dytb  = alloc(33554432);
  u16* weffA = alloc(21504);             // [3][32][224] bf16
  float* bwA = (float*)alloc(192);       // [3][32] f32

  // zero flag (4B) + raw ([3][16] f32 @ +128) in one memset, then detect dtype.
  hipMemsetAsync(flag, 0, 320, stream);
  hipLaunchKernelGGL(kdetect, dim3(32), dim3(256), 0, stream, (const u16*)d_in[0], flag);

  CvtTab tb;
  {
    const void* ss[18] = { d_in[6], d_in[7], d_in[8], d_in[9], d_in[10], d_in[11],
      d_in[12], d_in[13], d_in[14], d_in[15], d_in[16], d_in[17], d_in[18], d_in[19],
      d_in[20], d_in[21], d_in[22], d_in[23] };
    u16* dd[18] = { encWf, encbf, encWg, encbg, skW, skb, nw, nb,
      g0W, g0b, g1W, g1b, g2W, g2b, sEW, sEb, eW, eb };
    const int nn[18] = { 24576, 192, 24576, 192, 24576, 192, 49152, 49152,
      2304, 24, 2304, 24, 2304, 24, 2048, 64, 768, 3 };
    for (int e = 0; e < 18; e++) { tb.s[e] = ss[e]; tb.d[e] = dd[e]; tb.n4[e] = nn[e]; }
  }
  hipLaunchKernelGGL(kcvt_small, dim3(192, 18), dim3(256), 0, stream, tb, flag);
  hipLaunchKernelGGL(kcvt4, dim3(4096), dim3(256), 0, stream, d_in[2], stgb, 1048576, flag);
  hipLaunchKernelGGL(kweff, dim3(28, 3), dim3(256), 0, stream,
      g0W, g1W, g2W, g0b, g1b, g2b, weffA, bwA);

  hipMemsetAsync(rdy, 0, 131072, stream);   // zeroes rdy+cdy (contiguous)
  hipLaunchKernelGGL(kcvtT, dim3(16,32,8), dim3(256), 0, stream,
      d_in[1], dyb, dytb, rdy, cdy, flag);
  hipLaunchKernelGGL(kfin, dim3(128), dim3(256), 0, stream, rdy);
  hipLaunchKernelGGL(krowsum, dim3(512), dim3(256), 0, stream,
      stgb, (const u16*)d_in[2], flag, rst, 2048);
  hipLaunchKernelGGL(khid0, dim3(32,8), dim3(256), 0, stream,
      d_in[0], d_in[3], d_in[4], d_in[5], hid, pbuf, flag);

  const long PB = 458752;
  const long SL = 65536;
  const long DYB = 4194304;

  for (int i = 0; i < 3; i++) {
    PG p1;
    p1.Ac0 = stgb; p1.Ac1 = dyb; p1.Ac2 = dytb;
    p1.Ar0 = (const u16*)d_in[2]; p1.Ar1 = (const u16*)d_in[1];
    p1.flag = flag;
    p1.ab0 = 0;   p1.ab1 = DYB; p1.ab2 = DYB;
    p1.X0 = pbuf; p1.X1 = pbuf; p1.X2 = pbuf;
    p1.R0 = rst;  p1.R1 = rdy;  p1.R2 = cdy;
    p1.rb0 = 0;   p1.rb1 = 2048; p1.rb2 = 2048;
    p1.O0 = pbuf + 1*SL; p1.O1 = pbuf + 3*SL; p1.O2 = pbuf + 5*SL;

    FR fr;
    fr.p = p1;
    fr.H = hid;
    fr.Wf1 = encWf + (i*2+0)*16384; fr.bf1 = encbf + (i*2+0)*128;
    fr.Wg1 = encWg + (i*2+0)*16384; fr.bg1 = encbg + (i*2+0)*128;
    fr.Wf2 = encWf + (i*2+1)*16384; fr.bf2 = encbf + (i*2+1)*128;
    fr.Wg2 = encWg + (i*2+1)*16384; fr.bg2 = encbg + (i*2+1)*128;
    fr.out = hb2;
    hipLaunchKernelGGL(kfront, dim3(32,8,4), dim3(256), 0, stream, fr, PB, PB);

    BK bk;
    bk.p = p1;
    bk.p.X0 = pbuf + 1*SL; bk.p.X1 = pbuf + 3*SL; bk.p.X2 = pbuf + 5*SL;
    bk.p.O0 = pbuf + 2*SL; bk.p.O1 = pbuf + 4*SL; bk.p.O2 = pbuf + 6*SL;
    bk.A = hb2; bk.W = skW + i*32768; bk.bias = skb + i*256;
    bk.skipbuf = skip; bk.addprev = (i>0)?1:0;
    hipLaunchKernelGGL(kback, dim3(32,8,4), dim3(256), 0, stream, bk, PB, PB);

    hipLaunchKernelGGL((kprop<1,1>), dim3(128,1,8), dim3(256), 0, stream,
        pbuf, PB, 2048, 224, weffA + i*7168, 0L, 224, pbuf, PB,
        (const float*)nullptr, 0L, bwA + i*32, (u16*)nullptr, xpre, 65536L, raw + i*16);
    hipLaunchKernelGGL(kapply, dim3(32,8), dim3(256), 0, stream,
        xpre, raw + i*16, nw + i*65536, nb + i*65536, pbuf, hid);
  }
  hipLaunchKernelGGL(kskip, dim3(256), dim3(256), 0, stream,
      hid, 128, 32, sEW, 32, sEb, skip, 1, 1, xsb);
  hipLaunchKernelGGL(kend, dim3(256), dim3(256), 0, stream, xsb, eW, eb, d_out, flag);
}

// Round 9
// 714.855 us; speedup vs baseline: 1.1066x; 1.1066x over previous
//
#include <hip/hip_runtime.h>
#include <stdint.h>

// Net_18021682774696 — MTGNN-ish: 3x { TCN(2 gated units) ; skip ; 3x mixprop ; LN+ReLU } + end convs.
// Round 14: exact R4 (716us) structure revert; single change: kprops LDS 4->3 buffers
// (48->36 KB), prefetch distance 2, vmcnt(3) steady-state -> 4 blocks/CU (16 waves/CU,
// +33% TLP) to attack the latency-bound prop kernels. R8's co-scheduling (merged
// launches) regressed hard (occupancy 15.7%) and is fully reverted.

typedef uint16_t u16;
typedef uint32_t u32;
typedef __attribute__((ext_vector_type(8))) short s8v;
typedef __attribute__((ext_vector_type(4))) float f4v;

#define MFMA16(a,b,c) __builtin_amdgcn_mfma_f32_16x16x32_bf16(a,b,c,0,0,0)

__device__ __forceinline__ float b2f(u16 u){ union{u32 i; float f;} x; x.i=(u32)u<<16; return x.f; }
__device__ __forceinline__ u16 f2b(float f){
  u32 u = __builtin_bit_cast(u32, f);
  u32 r = (u + 0x7fffu + ((u >> 16) & 1u)) >> 16;   // RNE
  return (u16)r;
}

// async global->LDS, 16B per lane; LDS dest is wave-uniform base + lane*16.
__device__ __forceinline__ void gld16(const void* g, void* l) {
  __builtin_amdgcn_global_load_lds(
      (const __attribute__((address_space(1))) void*)g,
      (__attribute__((address_space(3))) void*)l, 16, 0, 0);
}

// ---------------------------------------------------------------------------
// kdetect: fp32 (flag=1) vs bf16 (flag=0). 32 blocks scan 128 KB; atomicOr.
// flag must be zeroed before launch.
// ---------------------------------------------------------------------------
__global__ __launch_bounds__(256) void kdetect(const u16* __restrict__ x, int* __restrict__ flag)
{
  const int i = blockIdx.x*256 + threadIdx.x;
  const uint4 v = ((const uint4*)x)[i];
  const u32 w[4] = {v.x, v.y, v.z, v.w};
  int cnt = 0;
  #pragma unroll
  for (int e = 0; e < 4; e++) {
    if ((w[e] & 0x7F80u) == 0x7F80u) cnt++;
    if (((w[e] >> 16) & 0x7F80u) == 0x7F80u) cnt++;
  }
  const unsigned long long m = __ballot(cnt != 0);
  if (m && (threadIdx.x & 63) == 0) atomicOr(flag, 1);
}

// kcvt4: canonicalize one array into bf16 (4 elements/thread). fp32 path only.
__global__ __launch_bounds__(256) void kcvt4(const void* __restrict__ src, u16* __restrict__ dst,
                                             int n4, const int* __restrict__ flag)
{
  if (!*flag) return;
  const int i = blockIdx.x*256 + threadIdx.x;
  if (i >= n4) return;
  const float4 v = ((const float4*)src)[i];
  u16 o[4]; o[0]=f2b(v.x); o[1]=f2b(v.y); o[2]=f2b(v.z); o[3]=f2b(v.w);
  *(uint2*)(dst + (long)i*4) = *(uint2*)o;
}

// kcvt_small: 18 small weight inputs in one launch.
struct CvtTab { const void* s[18]; u16* d[18]; int n4[18]; };
__global__ __launch_bounds__(256) void kcvt_small(CvtTab tb, const int* __restrict__ flag)
{
  const int e = blockIdx.y;
  const int i = blockIdx.x*256 + threadIdx.x;
  if (i >= tb.n4[e]) return;
  if (*flag) {
    const float4 v = ((const float4*)tb.s[e])[i];
    u16 o[4]; o[0]=f2b(v.x); o[1]=f2b(v.y); o[2]=f2b(v.z); o[3]=f2b(v.w);
    *(uint2*)(tb.d[e] + (long)i*4) = *(uint2*)o;
  } else {
    *(uint2*)(tb.d[e] + (long)i*4) = ((const uint2*)tb.s[e])[i];
  }
}

// ---------------------------------------------------------------------------
// kcvtT: dy -> dyb (fp32 path) + dytb (transposed) + row/col sums. (R4 version)
// ---------------------------------------------------------------------------
__global__ __launch_bounds__(256) void kcvtT(
    const void* __restrict__ src, u16* __restrict__ dyb, u16* __restrict__ dytb,
    float* __restrict__ rsum, float* __restrict__ csum, const int* __restrict__ flag)
{
  __shared__ alignas(16) u32 tt[64][32];
  const int tid = threadIdx.x;
  const int b = blockIdx.z;
  const long r0 = (long)blockIdx.y*64;
  const long c0 = (long)blockIdx.x*64;
  const int rp = tid>>3, c8 = (tid&7)*8;   // row-pair 0..31, col-group
  const long base = (long)b*4194304;
  const int fl = *flag;

  u16 lo[8], hi[8];
  const long gl = base + (r0 + 2*rp)*2048 + c0 + c8;
  const long gh = gl + 2048;
  if (fl) {
    const float* sl = (const float*)src + gl;
    const float* sh = (const float*)src + gh;
    const float4 a0 = ((const float4*)sl)[0], a1 = ((const float4*)sl)[1];
    const float4 b0 = ((const float4*)sh)[0], b1 = ((const float4*)sh)[1];
    lo[0]=f2b(a0.x); lo[1]=f2b(a0.y); lo[2]=f2b(a0.z); lo[3]=f2b(a0.w);
    lo[4]=f2b(a1.x); lo[5]=f2b(a1.y); lo[6]=f2b(a1.z); lo[7]=f2b(a1.w);
    hi[0]=f2b(b0.x); hi[1]=f2b(b0.y); hi[2]=f2b(b0.z); hi[3]=f2b(b0.w);
    hi[4]=f2b(b1.x); hi[5]=f2b(b1.y); hi[6]=f2b(b1.z); hi[7]=f2b(b1.w);
    *(uint4*)(dyb + gl) = *(uint4*)lo;    // bf16 copy needed only when converting
    *(uint4*)(dyb + gh) = *(uint4*)hi;
  } else {
    *(uint4*)lo = *((const uint4*)((const u16*)src + gl));
    *(uint4*)hi = *((const uint4*)((const u16*)src + gh));
  }
  float rsl = 0.f, rsh = 0.f;
  #pragma unroll
  for (int e = 0; e < 8; e++) {
    rsl += b2f(lo[e]); rsh += b2f(hi[e]);
    const int c = c8 + e;
    tt[c][rp ^ ((c & 0x38) >> 1)] = (u32)lo[e] | ((u32)hi[e] << 16);
  }
  rsl += __shfl_down(rsl, 4, 8); rsl += __shfl_down(rsl, 2, 8); rsl += __shfl_down(rsl, 1, 8);
  rsh += __shfl_down(rsh, 4, 8); rsh += __shfl_down(rsh, 2, 8); rsh += __shfl_down(rsh, 1, 8);
  if ((tid & 7) == 0) {
    atomicAdd(rsum + b*2048 + r0 + 2*rp,     rsl);
    atomicAdd(rsum + b*2048 + r0 + 2*rp + 1, rsh);
  }
  __syncthreads();

  // phase 2: thread -> output row c (input column), 16 input rows starting 2*j4.
  const int c = tid>>2, j4 = (tid&3)*8;
  const int sw = (c & 0x38) >> 1;
  u32 q[8];
  *(uint4*)&q[0] = *(const uint4*)&tt[c][j4 ^ sw];
  *(uint4*)&q[4] = *(const uint4*)&tt[c][(j4 + 4) ^ sw];
  float cs = 0.f;
  #pragma unroll
  for (int e = 0; e < 8; e++) { cs += b2f((u16)q[e]); cs += b2f((u16)(q[e] >> 16)); }
  cs += __shfl_down(cs, 2, 4); cs += __shfl_down(cs, 1, 4);
  u16* dp = dytb + base + (c0 + c)*2048 + r0 + 2*j4;
  *(uint4*)(dp)     = *(uint4*)&q[0];
  *(uint4*)(dp + 8) = *(uint4*)&q[4];
  if ((tid & 3) == 0) atomicAdd(csum + b*2048 + c0 + c, cs);
}

__global__ void kfin(float* __restrict__ v){   // v = 1/(1+v)
  const int i = blockIdx.x*256 + threadIdx.x;
  v[i] = 1.f/(1.f + v[i]);
}

// ---------------------------------------------------------------------------
// kprops: 3-graph, global_load_lds staged. Round 14: 3 LDS buffers (36 KB),
//   prefetch distance 2, steady-state vmcnt(3), one raw s_barrier per K-step.
//   4 blocks/CU (was 3 at 48 KB). grid (32, 8, 3).
// ---------------------------------------------------------------------------
struct PG {
  const u16* Ac0; const u16* Ac1; const u16* Ac2;   // converted bf16
  const u16* Ar0; const u16* Ar1;                   // raw inputs (bf16 fast path)
  const int* flag;
  long ab0, ab1, ab2;
  const u16* X0; const u16* X1; const u16* X2;
  const float* R0; const float* R1; const float* R2;
  long rb0, rb1, rb2;
  u16* O0; u16* O1; u16* O2;
};

__global__ __launch_bounds__(256) void kprops(PG p, long x_bs, long o_bs)
{
  __shared__ u16 Al[3][64][64];   // 24 KB
  __shared__ u16 Xl[3][32][64];   // 12 KB
  const int tid = threadIdx.x, wave = tid>>6, lane = tid&63;
  const int lw = lane&15, quad = lane>>4;
  const int wr = wave>>1, wc = wave&1;
  const int v0 = blockIdx.x*64;
  const int b = blockIdx.y, g = blockIdx.z;
  const int fl = *p.flag;
  const u16* Ag; long ab; const u16* Xg; const float* Rg; long rb_; u16* Og;
  if (g == 0)      { Ag = fl ? p.Ac0 : p.Ar0; ab = p.ab0; Xg = p.X0; Rg = p.R0; rb_ = p.rb0; Og = p.O0; }
  else if (g == 1) { Ag = fl ? p.Ac1 : p.Ar1; ab = p.ab1; Xg = p.X1; Rg = p.R1; rb_ = p.rb1; Og = p.O1; }
  else             { Ag = p.Ac2;              ab = p.ab2; Xg = p.X2; Rg = p.R2; rb_ = p.rb2; Og = p.O2; }
  const u16* Ab = Ag + (long)b*ab;
  const u16* Xb = Xg + (long)b*x_bs;

  // staging decode: wave-uniform LDS base + lane*16; source col pre-swizzled.
  const int srow = wave*8 + (lane>>3);          // 0..31 within a 32-row group
  const int skc  = lane&7;
  const long soff = (long)((skc ^ (srow&7))*8); // swizzled 8-elem column
  const u16* srcA0 = Ab + (long)(v0 + srow)*2048 + soff;        // rows  0..31
  const u16* srcA1 = Ab + (long)(v0 + 32 + srow)*2048 + soff;   // rows 32..63
  const u16* srcX  = Xb + (long)srow*2048 + soff;               // c rows 0..31

#define STAGE(bb_, tt) do { const long k0_=(long)(tt)*64;                           \
    gld16(srcA0 + k0_, (void*)((char*)&Al[bb_][0][0]  + wave*1024));                \
    gld16(srcA1 + k0_, (void*)((char*)&Al[bb_][32][0] + wave*1024));                \
    gld16(srcX  + k0_, (void*)((char*)&Xl[bb_][0][0]  + wave*1024)); } while(0)

  f4v acc0 = {0.f,0.f,0.f,0.f}, acc1 = {0.f,0.f,0.f,0.f};
  const int arow0 = wr*32 + lw;
  const int arow1 = wr*32 + 16 + lw;
  const int xrow  = wc*16 + lw;
  const int sw    = lw & 7;              // arow0&7 == arow1&7 == xrow&7 == lw&7
  const int q0    = (quad ^ sw)*8;       // k32=0 slot (elems)
  const int q1    = ((quad ^ sw) ^ 4)*8; // k32=1 slot

  STAGE(0, 0); STAGE(1, 1);              // 6 loads in flight per wave

  int rb = 0, sb = 2;
  #pragma unroll 1
  for (int t = 0; t < 32; t++) {
    if (t <= 30) asm volatile("s_waitcnt vmcnt(3)" ::: "memory");
    else         asm volatile("s_waitcnt vmcnt(0)" ::: "memory");
    __builtin_amdgcn_s_barrier();
    __builtin_amdgcn_sched_barrier(0);
    s8v x0  = *(const s8v*)&Xl[rb][xrow][q0];
    s8v a00 = *(const s8v*)&Al[rb][arow0][q0];
    s8v a10 = *(const s8v*)&Al[rb][arow1][q0];
    s8v x1  = *(const s8v*)&Xl[rb][xrow][q1];
    s8v a01 = *(const s8v*)&Al[rb][arow0][q1];
    s8v a11 = *(const s8v*)&Al[rb][arow1][q1];
    acc0 = MFMA16(a00, x0, acc0);
    acc1 = MFMA16(a10, x0, acc1);
    acc0 = MFMA16(a01, x1, acc0);
    acc1 = MFMA16(a11, x1, acc1);
    if (t <= 29) STAGE(sb, t+2);
    rb = (rb == 2) ? 0 : rb + 1;
    sb = (sb == 2) ? 0 : sb + 1;
  }
#undef STAGE

  // epilogue: wave owns 32v x 16c; D[row=quad*4+r, col=lw] per fragment.
  const int c = wc*16 + lw;
  const float* rp = Rg + (long)b*rb_;
  u16* ob = Og + (long)b*o_bs;
  #pragma unroll
  for (int f = 0; f < 2; f++) {
    const f4v s = f ? acc1 : acc0;
    const int vb = v0 + wr*32 + f*16 + quad*4;
    const u16* dp = Xb + (long)c*2048 + vb;
    u16 pk[4];
    #pragma unroll
    for (int r = 0; r < 4; r++) pk[r] = f2b((s[r] + b2f(dp[r])) * rp[vb + r]);
    *(uint2*)(ob + (long)c*2048 + vb) = *(uint2*)pk;
  }
}

// ---------------------------------------------------------------------------
// kprop (LDS-staged, kept for the TRANSA=1 combine pass):
//   MODE 1: out = acc + bias[c] + D[c,v] -> f32   (R4 version, no stats)
// ---------------------------------------------------------------------------
template<int TRANSA, int MODE>
__global__ __launch_bounds__(256) void kprop(
    const u16* __restrict__ A, long a_bs, int lda, int K,
    const u16* __restrict__ X, long x_bs, int ldx,
    const u16* __restrict__ D, long d_bs,
    const float* __restrict__ rinv, long r_bs,
    const float* __restrict__ bias,
    u16* __restrict__ out0, float* __restrict__ out1, long o_bs)
{
  __shared__ u16 As[4][2][16][40];
  __shared__ f4v red[4][2][64];
  const int tid = threadIdx.x;
  const int wave = tid >> 6, lane = tid & 63;
  const int lw = lane & 15, quad = lane >> 4;
  const int v0 = blockIdx.x * 16;
  const int ball = blockIdx.z + blockIdx.y;
  const u16* Ab = A + (long)ball * a_bs;
  const u16* Xb = X + (long)ball * x_bs;
  const int KC = K >> 5;

  f4v acc0 = {0.f,0.f,0.f,0.f}, acc1 = {0.f,0.f,0.f,0.f};

  int r0, c0_;
  if (TRANSA == 0) { r0 = lane >> 2; c0_ = (lane & 3) * 8; }
  else             { r0 = lane >> 1; c0_ = (lane & 1) * 8; }

  int ci = wave;
  bool has = ci < KC;
  uint4 d = make_uint4(0,0,0,0);
  if (has) {
    d = (TRANSA == 0)
      ? *(const uint4*)(Ab + (long)(v0 + r0) * lda + ci * 32 + c0_)
      : *(const uint4*)(Ab + (long)(ci * 32 + r0) * lda + v0 + c0_);
  }
  int buf = 0;
  while (has) {
    if (TRANSA == 0) {
      *(uint4*)&As[wave][buf][r0][c0_] = d;
    } else {
      u16 tmp[8]; *(uint4*)tmp = d;
      #pragma unroll
      for (int e = 0; e < 8; e++) As[wave][buf][c0_ + e][r0] = tmp[e];
    }
    const int cn = ci + 4;
    const bool hn = cn < KC;
    if (hn) {
      d = (TRANSA == 0)
        ? *(const uint4*)(Ab + (long)(v0 + r0) * lda + cn * 32 + c0_)
        : *(const uint4*)(Ab + (long)(cn * 32 + r0) * lda + v0 + c0_);
    }
    s8v af = *(const s8v*)&As[wave][buf][lw][quad * 8];
    const u16* xk = Xb + ci * 32 + quad * 8;
    s8v b0 = *(const s8v*)(xk + (long)lw * ldx);
    s8v b1 = *(const s8v*)(xk + (long)(16 + lw) * ldx);
    acc0 = MFMA16(af, b0, acc0);
    acc1 = MFMA16(af, b1, acc1);
    ci = cn; has = hn; buf ^= 1;
  }
  red[wave][0][lane] = acc0;
  red[wave][1][lane] = acc1;
  __syncthreads();
  if (wave == 0) {
    const int vb = v0 + quad * 4;
    #pragma unroll
    for (int nt = 0; nt < 2; nt++) {
      f4v a = red[0][nt][lane] + red[1][nt][lane] + red[2][nt][lane] + red[3][nt][lane];
      const int c = nt * 16 + lw;
      const u16* dp = D + (long)ball * d_bs + (long)c * 2048 + vb;
      if (MODE == 0) {
        const float* rp = rinv + (long)ball * r_bs + vb;
        u16 pk[4];
        #pragma unroll
        for (int r = 0; r < 4; r++) pk[r] = f2b((a[r] + b2f(dp[r])) * rp[r]);
        *(uint2*)(out0 + (long)ball * o_bs + (long)c * 2048 + vb) = *(uint2*)pk;
      } else {
        const float bs = bias[c];
        float4 st;
        st.x = a[0] + bs + b2f(dp[0]);
        st.y = a[1] + bs + b2f(dp[1]);
        st.z = a[2] + bs + b2f(dp[2]);
        st.w = a[3] + bs + b2f(dp[3]);
        *(float4*)(out1 + (long)ball * o_bs + (long)c * 2048 + vb) = st;
      }
    }
  }
}

// ---------------------------------------------------------------------------
// ktcn (LDS-free): out[j,o] = tanh(H@Wf^T+bf)*sigmoid(H@Wg^T+bg)
// ---------------------------------------------------------------------------
__global__ __launch_bounds__(256) void ktcn(
    const u16* __restrict__ H, const u16* __restrict__ Wf, const u16* __restrict__ bfv,
    const u16* __restrict__ Wg, const u16* __restrict__ bgv, u16* __restrict__ out)
{
  const int tid = threadIdx.x, wave = tid>>6, lane = tid&63, lw = lane&15, quad = lane>>4;
  const long j0 = (long)blockIdx.x*64 + wave*16;
  const f4v zero = {0.f,0.f,0.f,0.f};
  f4v accf[8], accg[8];
  #pragma unroll
  for (int nt=0; nt<8; nt++){ accf[nt] = zero; accg[nt] = zero; }
  const u16* Arow = H + (j0 + lw)*128 + quad*8;
  #pragma unroll
  for (int k0 = 0; k0 < 128; k0 += 32) {
    s8v a = *(const s8v*)(Arow + k0);
    #pragma unroll
    for (int nt = 0; nt < 8; nt++) {
      const int o = nt*16 + lw;
      s8v bf_ = *(const s8v*)(Wf + o*128 + k0 + quad*8);
      s8v bg_ = *(const s8v*)(Wg + o*128 + k0 + quad*8);
      accf[nt] = MFMA16(a, bf_, accf[nt]);
      accg[nt] = MFMA16(a, bg_, accg[nt]);
    }
  }
  #pragma unroll
  for (int nt = 0; nt < 8; nt++) {
    const int o = nt*16 + lw;
    const float fb = b2f(bfv[o]), gb = b2f(bgv[o]);
    #pragma unroll
    for (int rr = 0; rr < 4; rr++) {
      const long j = j0 + quad*4 + rr;
      const float f = accf[nt][rr] + fb, g = accg[nt][rr] + gb;
      const float e2 = __expf(2.f*f);
      const float th = 1.f - 2.f/(e2 + 1.f);
      const float sg = 1.f/(1.f + __expf(-g));
      out[j*128 + o] = f2b(th*sg);
    }
  }
}

// ---------------------------------------------------------------------------
// kskip (LDS-free): C[j,o] = A@W^T + bias (+ prev skip).  N=256.
// ---------------------------------------------------------------------------
__global__ __launch_bounds__(256) void kskip(
    const u16* __restrict__ A, int lda, int K,
    const u16* __restrict__ W, int ldb,
    const u16* __restrict__ bias,
    float* __restrict__ skipbuf, int addprev, int mode, u16* __restrict__ outb)
{
  const int tid = threadIdx.x, wave = tid>>6, lane = tid&63, lw = lane&15, quad = lane>>4;
  const long j0 = (long)blockIdx.x*64 + wave*16;
  const f4v zero = {0.f,0.f,0.f,0.f};
  f4v acc[16];
  #pragma unroll
  for (int nt=0; nt<16; nt++) acc[nt] = zero;
  const u16* Arow = A + (j0 + lw)*(long)lda + quad*8;
  for (int k0 = 0; k0 < K; k0 += 32) {
    s8v a = *(const s8v*)(Arow + k0);
    #pragma unroll
    for (int nt = 0; nt < 16; nt++) {
      const int o = nt*16 + lw;
      s8v b = *(const s8v*)(W + (long)o*ldb + k0 + quad*8);
      acc[nt] = MFMA16(a, b, acc[nt]);
    }
  }
  #pragma unroll
  for (int nt = 0; nt < 16; nt++) {
    const int o = nt*16 + lw;
    const float bv = b2f(bias[o]);
    #pragma unroll
    for (int rr = 0; rr < 4; rr++) {
      const long j = j0 + quad*4 + rr;
      float v = acc[nt][rr] + bv;
      if (addprev) v += skipbuf[j*256 + o];
      if (mode == 0) skipbuf[j*256 + o] = v;
      else           outb[j*256 + o] = f2b(v);
    }
  }
}

// ---------------------------------------------------------------------------
// kend (LDS-free): out[b,t,n] = xs@endW^T + end_b.  N=12, K=256.
// ---------------------------------------------------------------------------
__global__ __launch_bounds__(256) void kend(
    const u16* __restrict__ A, const u16* __restrict__ W, const u16* __restrict__ bias,
    void* __restrict__ outv, const int* __restrict__ flag)
{
  const int tid = threadIdx.x, wave = tid>>6, lane = tid&63, lw = lane&15, quad = lane>>4;
  const long j0 = (long)blockIdx.x*64 + wave*16;
  f4v acc = {0.f,0.f,0.f,0.f};
  const u16* Arow = A + (j0 + lw)*256 + quad*8;
  #pragma unroll
  for (int k0 = 0; k0 < 256; k0 += 32) {
    s8v a = *(const s8v*)(Arow + k0);
    s8v b = {0,0,0,0,0,0,0,0};
    if (lw < 12) b = *(const s8v*)(W + lw*256 + k0 + quad*8);
    acc = MFMA16(a, b, acc);
  }
  if (lw < 12) {
    const float bv = b2f(bias[lw]);
    const int fl = *flag;
    #pragma unroll
    for (int rr = 0; rr < 4; rr++) {
      const long j = j0 + quad*4 + rr;
      const long oi = (j >> 11)*24576 + lw*2048 + (j & 2047);
      const float val = acc[rr] + bv;
      if (fl) ((float*)outv)[oi] = val;
      else    ((u16*)outv)[oi]   = f2b(val);
    }
  }
}

// ---------------------------------------------------------------------------
// khid0: fused convert+transpose of {x, spat, tde, twe} -> hid (channel-last)
//        and x -> pbuf slot0 (channel-first bf16).
// ---------------------------------------------------------------------------
__global__ __launch_bounds__(256) void khid0(
    const void* __restrict__ x, const void* __restrict__ spat,
    const void* __restrict__ tde, const void* __restrict__ twe,
    u16* __restrict__ hid, u16* __restrict__ slot0, const int* __restrict__ flag)
{
  __shared__ u16 t[32][72];
  const int tid = threadIdx.x, b = blockIdx.y, v0 = blockIdx.x*64;
  const int fl = *flag;
  const void* srcs[4] = {x, spat, tde, twe};
  #pragma unroll
  for (int e = 0; e < 4; e++) {
    const int c = tid>>3, v8 = (tid&7)*8;
    const long boff = (long)c*2048 + v0 + v8;
    u16 o8[8];
    if (fl) {
      const float* sp = (const float*)srcs[e] + (long)b*65536 + boff;
      const float4 a = ((const float4*)sp)[0], bb = ((const float4*)sp)[1];
      o8[0]=f2b(a.x); o8[1]=f2b(a.y); o8[2]=f2b(a.z); o8[3]=f2b(a.w);
      o8[4]=f2b(bb.x); o8[5]=f2b(bb.y); o8[6]=f2b(bb.z); o8[7]=f2b(bb.w);
    } else {
      *(uint4*)o8 = *(const uint4*)((const u16*)srcs[e] + (long)b*65536 + boff);
    }
    if (e == 0) *(uint4*)(slot0 + (long)b*458752 + boff) = *(uint4*)o8;
    *(uint4*)&t[c][v8] = *(uint4*)o8;
    __syncthreads();
    const int jl = tid>>2, c8 = (tid&3)*8;
    u16 q8[8];
    #pragma unroll
    for (int i = 0; i < 8; i++) q8[i] = t[c8 + i][jl];
    *(uint4*)(hid + ((long)b*2048 + v0 + jl)*128 + e*32 + c8) = *(uint4*)q8;
    __syncthreads();
  }
}

// krowsum: row sums of the static graph; picks converted vs raw source by flag.
__global__ __launch_bounds__(256) void krowsum(const u16* __restrict__ srcA, const u16* __restrict__ srcB,
                                               const int* __restrict__ flag,
                                               float* __restrict__ outv, int nrows)
{
  const u16* src = (*flag) ? srcA : srcB;
  const int wave = threadIdx.x>>6, lane = threadIdx.x&63;
  const int row = blockIdx.x*4 + wave;
  if (row >= nrows) return;
  const u16* p = src + (long)row*2048 + lane*8;
  float s = 0.f;
  #pragma unroll
  for (int it = 0; it < 4; it++) {
    u16 v[8]; *(uint4*)v = *(const uint4*)(p + it*512);
    #pragma unroll
    for (int e = 0; e < 8; e++) s += b2f(v[e]);
  }
  #pragma unroll
  for (int off = 32; off; off >>= 1) s += __shfl_down(s, off, 64);
  if (lane == 0) outv[row] = 1.f/(1.f + s);
}

__global__ __launch_bounds__(256) void kweff(
    const u16* __restrict__ g0W, const u16* __restrict__ g1W, const u16* __restrict__ g2W,
    const u16* __restrict__ g0b, const u16* __restrict__ g1b, const u16* __restrict__ g2b,
    int ioff, int boff, u16* __restrict__ weff, float* __restrict__ bw)
{
  const int idx = blockIdx.x*256 + threadIdx.x;
  if (idx < 32) bw[idx] = b2f(g0b[boff+idx]) + b2f(g1b[boff+idx]) + b2f(g2b[boff+idx]);
  if (idx >= 7168) return;
  const int o = idx / 224, m = idx % 224;
  const u16* Ws[3] = {g0W + ioff, g1W + ioff, g2W + ioff};
  float val;
  if (m < 32) {
    val = 0.f;
    #pragma unroll
    for (int g = 0; g < 3; g++) {
      const float w0 = b2f(Ws[g][o*96 + m]);
      const float w1 = b2f(Ws[g][o*96 + 32 + m]);
      const float w2 = b2f(Ws[g][o*96 + 64 + m]);
      val += w0 + 0.05f*(w1 + w2);
    }
  } else {
    const int f = (m - 32) >> 5, cc = m & 31;
    const int g = f >> 1, typ = f & 1;
    const float w1 = b2f(Ws[g][o*96 + 32 + cc]);
    const float w2 = b2f(Ws[g][o*96 + 64 + cc]);
    val = (typ == 0) ? (0.95f*w1 + 0.0475f*w2) : (0.9025f*w2);
  }
  weff[o*224 + m] = f2b(val);
}

// kstats: per-batch partial (sum, sumsq) over 8192-elem segment -> atomics.
__global__ __launch_bounds__(256) void kstats(const float* __restrict__ xpre, float* __restrict__ raw)
{
  const int b = blockIdx.y, tid = threadIdx.x;
  const float4* p = (const float4*)(xpre + (long)b*65536 + (long)blockIdx.x*8192);
  float s = 0.f, q = 0.f;
  #pragma unroll
  for (int i = 0; i < 8; i++) {
    const float4 v = p[tid + i*256];
    s += v.x + v.y + v.z + v.w;
    q += v.x*v.x + v.y*v.y + v.z*v.z + v.w*v.w;
  }
  __shared__ float ss[256], qq[256];
  ss[tid] = s; qq[tid] = q;
  __syncthreads();
  for (int st = 128; st; st >>= 1) {
    if (tid < st) { ss[tid] += ss[tid+st]; qq[tid] += qq[tid+st]; }
    __syncthreads();
  }
  if (tid == 0) { atomicAdd(raw + b*2, ss[0]); atomicAdd(raw + b*2 + 1, qq[0]); }
}

__global__ __launch_bounds__(256) void kapply(
    const float* __restrict__ xpre, const float* __restrict__ raw,
    const u16* __restrict__ nw, const u16* __restrict__ nb,
    u16* __restrict__ slot0, u16* __restrict__ hid)
{
  __shared__ u16 t[32][72];
  const int tid = threadIdx.x, b = blockIdx.y, v0 = blockIdx.x*64;
  const float mu = raw[b*2] * (1.f/65536.f);
  const float var = raw[b*2+1] * (1.f/65536.f) - mu*mu;
  const float rs = rsqrtf(var + 1e-5f);
  const int c = tid>>3, v8 = (tid&7)*8;
  const long boff = (long)c*2048 + v0 + v8;
  float4 xa = *(const float4*)(xpre + (long)b*65536 + boff);
  float4 xbv = *(const float4*)(xpre + (long)b*65536 + boff + 4);
  u16 wv[8], bv[8], o8[8];
  *(uint4*)wv = *(const uint4*)(nw + boff);
  *(uint4*)bv = *(const uint4*)(nb + boff);
  const float xs[8] = {xa.x, xa.y, xa.z, xa.w, xbv.x, xbv.y, xbv.z, xbv.w};
  #pragma unroll
  for (int e = 0; e < 8; e++) {
    float y = (xs[e] - mu) * rs * b2f(wv[e]) + b2f(bv[e]);
    y = fmaxf(y, 0.f);
    o8[e] = f2b(y);
    t[c][v8 + e] = o8[e];
  }
  *(uint4*)(slot0 + (long)b*458752 + boff) = *(uint4*)o8;
  __syncthreads();
  const int jl = tid>>2, c8 = (tid&3)*8;
  u16 q8[8];
  #pragma unroll
  for (int e = 0; e < 8; e++) q8[e] = t[c8 + e][jl];
  *(uint4*)(hid + ((long)b*2048 + v0 + jl)*128 + c8) = *(uint4*)q8;
}

// ---------------------------------------------------------------------------
extern "C" void kernel_launch(void* const* d_in, const int* in_sizes, int n_in,
                              void* d_out, int out_size, void* d_ws, size_t ws_size,
                              hipStream_t stream)
{
  (void)in_sizes; (void)n_in; (void)out_size; (void)ws_size;

  char* ws = (char*)d_ws;
  u16*   pbuf = (u16*)(ws + 0);          // [8][7][32][2048] bf16
  u16*   hid  = (u16*)(ws + 7340032);    // [16384][128] bf16
  u16*   hb1  = (u16*)(ws + 11534336);
  u16*   hb2  = (u16*)(ws + 15728640);
  float* skip = (float*)(ws + 19922944); // [16384][256] f32
  u16*   xsb  = (u16*)(ws + 36700160);   // [16384][256] bf16
  float* xpre = (float*)(ws + 45088768); // [8][32][2048] f32
  u16*   weff = (u16*)(ws + 47185920);
  float* bw   = (float*)(ws + 47202304);
  float* rst  = (float*)(ws + 47203328); // [2048]
  float* rdy  = (float*)(ws + 47211520); // [8][2048]  (contiguous with cdy)
  float* cdy  = (float*)(ws + 47277056); // [8][2048]
  int*   flag = (int*)(ws + 47343616);
  float* raw  = (float*)(ws + 47343744); // [3][16] LN partials

  size_t coff = 50331648;
  auto alloc = [&](size_t elems) -> u16* {
    u16* p = (u16*)(ws + coff);
    coff += ((elems*2 + 255)/256)*256;
    return p;
  };
  u16* dyb   = alloc(33554432);
  u16* stgb  = alloc(4194304);
  u16* encWf = alloc(98304);
  u16* encbf = alloc(768);
  u16* encWg = alloc(98304);
  u16* encbg = alloc(768);
  u16* skW   = alloc(98304);
  u16* skb   = alloc(768);
  u16* nw    = alloc(196608);
  u16* nb    = alloc(196608);
  u16* g0W   = alloc(9216);
  u16* g0b   = alloc(96);
  u16* g1W   = alloc(9216);
  u16* g1b   = alloc(96);
  u16* g2W   = alloc(9216);
  u16* g2b   = alloc(96);
  u16* sEW   = alloc(8192);
  u16* sEb   = alloc(256);
  u16* eW    = alloc(3072);
  u16* eb    = alloc(12);
  u16* dytb  = alloc(33554432);

  // zero flag (4B) + raw (192B @ +128) in one memset, then detect dtype.
  hipMemsetAsync(flag, 0, 320, stream);
  hipLaunchKernelGGL(kdetect, dim3(32), dim3(256), 0, stream, (const u16*)d_in[0], flag);

  CvtTab tb;
  {
    const void* ss[18] = { d_in[6], d_in[7], d_in[8], d_in[9], d_in[10], d_in[11],
      d_in[12], d_in[13], d_in[14], d_in[15], d_in[16], d_in[17], d_in[18], d_in[19],
      d_in[20], d_in[21], d_in[22], d_in[23] };
    u16* dd[18] = { encWf, encbf, encWg, encbg, skW, skb, nw, nb,
      g0W, g0b, g1W, g1b, g2W, g2b, sEW, sEb, eW, eb };
    const int nn[18] = { 24576, 192, 24576, 192, 24576, 192, 49152, 49152,
      2304, 24, 2304, 24, 2304, 24, 2048, 64, 768, 3 };
    for (int e = 0; e < 18; e++) { tb.s[e] = ss[e]; tb.d[e] = dd[e]; tb.n4[e] = nn[e]; }
  }
  hipLaunchKernelGGL(kcvt_small, dim3(192, 18), dim3(256), 0, stream, tb, flag);
  hipLaunchKernelGGL(kcvt4, dim3(4096), dim3(256), 0, stream, d_in[2], stgb, 1048576, flag);

  hipMemsetAsync(rdy, 0, 131072, stream);   // zeroes rdy+cdy (contiguous)
  hipLaunchKernelGGL(kcvtT, dim3(32,32,8), dim3(256), 0, stream,
      d_in[1], dyb, dytb, rdy, cdy, flag);
  hipLaunchKernelGGL(kfin, dim3(128), dim3(256), 0, stream, rdy);
  hipLaunchKernelGGL(krowsum, dim3(512), dim3(256), 0, stream,
      stgb, (const u16*)d_in[2], flag, rst, 2048);
  hipLaunchKernelGGL(khid0, dim3(32,8), dim3(256), 0, stream,
      d_in[0], d_in[3], d_in[4], d_in[5], hid, pbuf, flag);

  const long PB = 458752;
  const long SL = 65536;
  const long DYB = 4194304;

  for (int i = 0; i < 3; i++) {
    hipLaunchKernelGGL(ktcn, dim3(256), dim3(256), 0, stream,
        hid, encWf + (i*2+0)*16384, encbf + (i*2+0)*128, encWg + (i*2+0)*16384, encbg + (i*2+0)*128, hb1);
    hipLaunchKernelGGL(ktcn, dim3(256), dim3(256), 0, stream,
        hb1, encWf + (i*2+1)*16384, encbf + (i*2+1)*128, encWg + (i*2+1)*16384, encbg + (i*2+1)*128, hb2);
    hipLaunchKernelGGL(kskip, dim3(256), dim3(256), 0, stream,
        hb2, 128, 128, skW + i*32768, 128, skb + i*256, skip, (i>0)?1:0, 0, (u16*)nullptr);
    hipLaunchKernelGGL(kweff, dim3(28), dim3(256), 0, stream,
        g0W, g1W, g2W, g0b, g1b, g2b, i*3072, i*32, weff, bw);

    PG p1;
    p1.Ac0 = stgb; p1.Ac1 = dyb; p1.Ac2 = dytb;
    p1.Ar0 = (const u16*)d_in[2]; p1.Ar1 = (const u16*)d_in[1];
    p1.flag = flag;
    p1.ab0 = 0;   p1.ab1 = DYB; p1.ab2 = DYB;
    p1.X0 = pbuf; p1.X1 = pbuf; p1.X2 = pbuf;
    p1.R0 = rst;  p1.R1 = rdy;  p1.R2 = cdy;
    p1.rb0 = 0;   p1.rb1 = 2048; p1.rb2 = 2048;
    p1.O0 = pbuf + 1*SL; p1.O1 = pbuf + 3*SL; p1.O2 = pbuf + 5*SL;
    hipLaunchKernelGGL(kprops, dim3(32,8,3), dim3(256), 0, stream, p1, PB, PB);

    PG p2 = p1;
    p2.X0 = pbuf + 1*SL; p2.X1 = pbuf + 3*SL; p2.X2 = pbuf + 5*SL;
    p2.O0 = pbuf + 2*SL; p2.O1 = pbuf + 4*SL; p2.O2 = pbuf + 6*SL;
    hipLaunchKernelGGL(kprops, dim3(32,8,3), dim3(256), 0, stream, p2, PB, PB);

    hipLaunchKernelGGL((kprop<1,1>), dim3(128,1,8), dim3(256), 0, stream,
        pbuf, PB, 2048, 224, weff, 0L, 224, pbuf, PB, (const float*)nullptr, 0L, bw, (u16*)nullptr, xpre, 65536L);
    hipLaunchKernelGGL(kstats, dim3(8,8), dim3(256), 0, stream, xpre, raw + i*16);
    hipLaunchKernelGGL(kapply, dim3(32,8), dim3(256), 0, stream,
        xpre, raw + i*16, nw + i*65536, nb + i*65536, pbuf, hid);
  }
  hipLaunchKernelGGL(kskip, dim3(256), dim3(256), 0, stream,
      hid, 128, 32, sEW, 32, sEb, skip, 1, 1, xsb);
  hipLaunchKernelGGL(kend, dim3(256), dim3(256), 0, stream, xsb, eW, eb, d_out, flag);
}